// Round 1
// baseline (604.480 us; speedup 1.0000x reference)
//
#include <hip/hip_runtime.h>

#define N_QUBITS 24
#define NSTATE (1u << N_QUBITS)   // 16,777,216 amplitudes
#define GDIM 16

// One thread owns one "group" of 16 amplitudes (all amplitudes sharing the
// same non-target bits). Reads 16 complex amps, applies the 16x16 complex
// gate (staged interleaved in LDS, broadcast reads), writes back.
// In-place safe: groups partition the state; each amp belongs to exactly one
// group, and only the owning thread touches it.
__global__ __launch_bounds__(256) void apply_gate4(
    const float* src, float* dst,
    const int* __restrict__ targets_raw,
    const float* __restrict__ gates,
    int step)
{
    __shared__ float gsh[2 * GDIM * GDIM];  // interleaved (re, im) pairs
    __shared__ int tsh[4];                  // unsorted targets (bit j of g)
    __shared__ int ssh[4];                  // sorted ascending (for expansion)

    const int tid = threadIdx.x;

    // Stage gate for this step: gates layout [step][2][16][16]
    const float* G = gates + (size_t)step * 512;
    {
        int i = tid;
        if (i < 256) {
            gsh[2 * i]     = G[i];         // real
            gsh[2 * i + 1] = G[256 + i];   // imag
        }
    }

    if (tid == 0) {
        // Detect whether targets buffer is int64 (pairs lo,hi with hi==0)
        // or int32. For the int32 case, some odd in-bounds word is nonzero
        // within the first two probes (each step's 4 targets are distinct),
        // so we never read out of bounds.
        bool is64 = true;
        for (int i = 0; i < 32; ++i) {
            if (targets_raw[2 * i + 1] != 0) { is64 = false; break; }
        }
        int t[4];
        #pragma unroll
        for (int j = 0; j < 4; ++j) {
            t[j] = is64 ? targets_raw[2 * (step * 4 + j)]
                        : targets_raw[step * 4 + j];
            tsh[j] = t[j];
        }
        // sort ascending for the zero-insertion expansion
        #pragma unroll
        for (int a = 0; a < 3; ++a)
            #pragma unroll
            for (int b = a + 1; b < 4; ++b)
                if (t[b] < t[a]) { int tmp = t[a]; t[a] = t[b]; t[b] = tmp; }
        #pragma unroll
        for (int j = 0; j < 4; ++j) ssh[j] = t[j];
    }
    __syncthreads();

    const int t0 = tsh[0], t1 = tsh[1], t2 = tsh[2], t3 = tsh[3];

    // group index -> base state index: insert 0 bits at sorted target positions
    unsigned base = blockIdx.x * 256u + (unsigned)tid;
    #pragma unroll
    for (int j = 0; j < 4; ++j) {
        const unsigned s = (unsigned)ssh[j];
        const unsigned low = base & ((1u << s) - 1u);
        base = ((base >> s) << (s + 1)) | low;
    }

    float sr[GDIM], si[GDIM];
    unsigned idx[GDIM];
    #pragma unroll
    for (int g = 0; g < GDIM; ++g) {
        const unsigned o = ((unsigned)(g & 1)        << t0)
                         | ((unsigned)((g >> 1) & 1) << t1)
                         | ((unsigned)((g >> 2) & 1) << t2)
                         | ((unsigned)((g >> 3) & 1) << t3);
        const unsigned id = base | o;
        idx[g] = id;
        sr[g] = src[id];
        si[g] = src[NSTATE + id];
    }

    #pragma unroll
    for (int g = 0; g < GDIM; ++g) {
        float ar = 0.f, ai = 0.f;
        #pragma unroll
        for (int h = 0; h < GDIM; ++h) {
            const float gr = gsh[2 * (g * GDIM + h)];
            const float gi = gsh[2 * (g * GDIM + h) + 1];
            ar = fmaf(gr, sr[h], ar);
            ar = fmaf(-gi, si[h], ar);
            ai = fmaf(gr, si[h], ai);
            ai = fmaf(gi, sr[h], ai);
        }
        dst[idx[g]] = ar;
        dst[NSTATE + idx[g]] = ai;
    }
}

extern "C" void kernel_launch(void* const* d_in, const int* in_sizes, int n_in,
                              void* d_out, int out_size, void* d_ws, size_t ws_size,
                              hipStream_t stream) {
    const float* state   = (const float*)d_in[0];
    const int*   targets = (const int*)d_in[1];
    const float* gates   = (const float*)d_in[2];
    float* out = (float*)d_out;

    const int groups = NSTATE / GDIM;          // 2^20
    const dim3 block(256);
    const dim3 grid(groups / 256);             // 4096 blocks

    // step 0: d_in -> d_out; steps 1..7: in place on d_out
    apply_gate4<<<grid, block, 0, stream>>>(state, out, targets, gates, 0);
    for (int s = 1; s < 8; ++s) {
        apply_gate4<<<grid, block, 0, stream>>>(out, out, targets, gates, s);
    }
}

// Round 2
// 580.546 us; speedup vs baseline: 1.0412x; 1.0412x over previous
//
#include <hip/hip_runtime.h>

#define N_QUBITS 24
#define NSTATE (1u << N_QUBITS)   // 16,777,216 amplitudes per plane
#define GDIM 16
#define TILE_BITS 12
#define TILE (1u << TILE_BITS)    // 4096 amps per block tile

// Block-tiled gate application with fully-coalesced float4 global traffic.
// Local index space S = 4 target bits + 8 lowest non-target bits (always
// contains bits 0..7 -> contiguous aligned 1KB runs per wave float4 load).
// Permutation (group gather/scatter) happens in XOR-swizzled LDS.
// Tiles partition the state -> in-place safe across src==dst.
__global__ __launch_bounds__(256) void apply_gate4(
    const float* __restrict__ src, float* __restrict__ dst,
    const int* __restrict__ targets_raw,
    const float* __restrict__ gates,
    int step)
{
    __shared__ float gsh[2 * GDIM * GDIM]; // interleaved (re,im)
    __shared__ float ldsR[TILE];
    __shared__ float ldsI[TILE];
    __shared__ int s12sh[12];   // sorted S bit positions
    __shared__ int possh[4];    // compacted pos (within S) of target j, ORIGINAL order
    __shared__ int ntpossh[8];  // compacted pos of non-target S bits, ascending

    const int tid = threadIdx.x;

    // stage gate: gates layout [step][2][16][16]
    const float* G = gates + (size_t)step * 512;
    gsh[2 * tid]     = G[tid];
    gsh[2 * tid + 1] = G[256 + tid];

    if (tid == 0) {
        // int64-vs-int32 targets detection (proven in R1)
        bool is64 = true;
        for (int i = 0; i < 32; ++i) {
            if (targets_raw[2 * i + 1] != 0) { is64 = false; break; }
        }
        int t[4];
        unsigned tmask = 0;
        #pragma unroll
        for (int j = 0; j < 4; ++j) {
            t[j] = is64 ? targets_raw[2 * (step * 4 + j)]
                        : targets_raw[step * 4 + j];
            tmask |= 1u << t[j];
        }
        // S = targets + 8 lowest non-target bits
        unsigned smask = tmask;
        int cnt = 0;
        for (int b = 0; b < N_QUBITS && cnt < 8; ++b)
            if (!((tmask >> b) & 1u)) { smask |= 1u << b; ++cnt; }
        int k = 0, k2 = 0;
        for (int b = 0; b < N_QUBITS; ++b) {
            if ((smask >> b) & 1u) {
                s12sh[k] = b;
                if (!((tmask >> b) & 1u)) ntpossh[k2++] = k;
                ++k;
            }
        }
        #pragma unroll
        for (int j = 0; j < 4; ++j)
            possh[j] = __popc(smask & ((1u << t[j]) - 1u));
    }
    __syncthreads();

    // block base: blockIdx bits spread over the 12 non-S positions
    unsigned base = blockIdx.x;
    #pragma unroll
    for (int i = 0; i < 12; ++i) {
        const unsigned s = (unsigned)s12sh[i];
        base = ((base >> s) << (s + 1)) | (base & ((1u << s) - 1u));
    }
    const unsigned sh8 = s12sh[8], sh9 = s12sh[9],
                   sh10 = s12sh[10], sh11 = s12sh[11];

    unsigned addr4[4], w4[4];
    #pragma unroll
    for (int p = 0; p < 4; ++p) {
        const unsigned a = (unsigned)(tid * 4 + p * 1024);
        addr4[p] = base
                 | (a & 255u)
                 | (((a >> 8) & 1u) << sh8)
                 | (((a >> 9) & 1u) << sh9)
                 | (((a >> 10) & 1u) << sh10)
                 | (((a >> 11) & 1u) << sh11);
        w4[p] = a ^ (((a >> 5) & 7u) << 2);  // float4-preserving XOR swizzle
    }

    // ---- load phase: coalesced float4 global -> swizzled LDS ----
    #pragma unroll
    for (int p = 0; p < 4; ++p) {
        *(float4*)(ldsR + w4[p]) = *(const float4*)(src + addr4[p]);
        *(float4*)(ldsI + w4[p]) = *(const float4*)(src + NSTATE + addr4[p]);
    }
    __syncthreads();

    // ---- gather + gate + scatter (thread owns one group; groups disjoint) ----
    unsigned gb = 0;
    #pragma unroll
    for (int i = 0; i < 8; ++i)
        gb |= (((unsigned)tid >> i) & 1u) << ntpossh[i];
    const int p0 = possh[0], p1 = possh[1], p2 = possh[2], p3 = possh[3];

    unsigned aa[GDIM];
    float sr[GDIM], si[GDIM];
    #pragma unroll
    for (int h = 0; h < GDIM; ++h) {
        const unsigned a = gb
            | (((unsigned)h & 1u) << p0)
            | ((((unsigned)h >> 1) & 1u) << p1)
            | ((((unsigned)h >> 2) & 1u) << p2)
            | ((((unsigned)h >> 3) & 1u) << p3);
        const unsigned w = a ^ (((a >> 5) & 7u) << 2);
        aa[h] = w;
        sr[h] = ldsR[w];
        si[h] = ldsI[w];
    }
    #pragma unroll
    for (int g = 0; g < GDIM; ++g) {
        float ar = 0.f, ai = 0.f;
        #pragma unroll
        for (int h = 0; h < GDIM; ++h) {
            const float gr = gsh[2 * (g * GDIM + h)];
            const float gi = gsh[2 * (g * GDIM + h) + 1];
            ar = fmaf(gr, sr[h], ar);
            ar = fmaf(-gi, si[h], ar);
            ai = fmaf(gr, si[h], ai);
            ai = fmaf(gi, sr[h], ai);
        }
        ldsR[aa[g]] = ar;
        ldsI[aa[g]] = ai;
    }
    __syncthreads();

    // ---- store phase: swizzled LDS -> coalesced float4 global ----
    #pragma unroll
    for (int p = 0; p < 4; ++p) {
        *(float4*)(dst + addr4[p])          = *(const float4*)(ldsR + w4[p]);
        *(float4*)(dst + NSTATE + addr4[p]) = *(const float4*)(ldsI + w4[p]);
    }
}

extern "C" void kernel_launch(void* const* d_in, const int* in_sizes, int n_in,
                              void* d_out, int out_size, void* d_ws, size_t ws_size,
                              hipStream_t stream) {
    const float* state   = (const float*)d_in[0];
    const int*   targets = (const int*)d_in[1];
    const float* gates   = (const float*)d_in[2];
    float* out = (float*)d_out;

    const dim3 block(256);
    const dim3 grid(NSTATE / TILE);  // 4096 blocks

    apply_gate4<<<grid, block, 0, stream>>>(state, out, targets, gates, 0);
    for (int s = 1; s < 8; ++s) {
        apply_gate4<<<grid, block, 0, stream>>>(out, out, targets, gates, s);
    }
}

// Round 3
// 519.553 us; speedup vs baseline: 1.1635x; 1.1174x over previous
//
#include <hip/hip_runtime.h>

#define NQ 24
#define NSTATE (1u << NQ)      // 2^24 amps per plane
#define TB 13                  // tile bits
#define TILE (1u << TB)        // 8192 amps
#define NTHR 512
#define MAXG 4                 // max fused gates per sweep
#define GROUP_STRIDE 80

// meta (ints in d_ws):
// [0] n_groups
// group g at 8 + g*GROUP_STRIDE:
//   [0]      n_gates (1..4)
//   [1..13]  S positions, ascending (13 tile bits -> global bit)
//   [14..24] complement positions, ascending (11)
//   [25+k*5] step index; [26+k*5 .. 29+k*5] compacted target positions (orig order)

__global__ void plan_kernel(const int* __restrict__ targets_raw, int* __restrict__ meta)
{
    if (threadIdx.x != 0 || blockIdx.x != 0) return;
    // int64-vs-int32 detection; probes words 1,3,5,7 (in-bounds both ways;
    // int32 case breaks by i=1 since row-0 targets are distinct => at most one zero)
    bool is64 = true;
    for (int i = 0; i < 4; ++i)
        if (targets_raw[2 * i + 1] != 0) { is64 = false; break; }

    int t[8][4];
    unsigned tm[8];
    for (int s = 0; s < 8; ++s) {
        unsigned m = 0;
        for (int j = 0; j < 4; ++j) {
            int v = is64 ? targets_raw[2 * (s * 4 + j)] : targets_raw[s * 4 + j];
            t[s][j] = v; m |= 1u << v;
        }
        tm[s] = m;
    }

    int ng = 0, sp = 0;
    while (sp < 8) {
        unsigned mask = 0xFu;          // force bits 0..3 (coalescing)
        int cnt = 0, steps[MAXG];
        while (sp < 8 && cnt < MAXG) {
            unsigned nm = mask | tm[sp];
            if (__popc(nm) <= TB) { mask = nm; steps[cnt++] = sp++; }
            else break;
        }
        unsigned sm = mask;
        int need = TB - __popc(sm);
        for (int b = 0; b < NQ && need > 0; ++b)
            if (!((sm >> b) & 1u)) { sm |= 1u << b; --need; }

        int* g = meta + 8 + ng * GROUP_STRIDE;
        g[0] = cnt;
        int spos[NQ];
        int si = 0, ci = 0;
        for (int b = 0; b < NQ; ++b) {
            if ((sm >> b) & 1u) { spos[b] = si; g[1 + si] = b; ++si; }
            else                { spos[b] = -1; g[14 + ci] = b; ++ci; }
        }
        for (int k = 0; k < cnt; ++k) {
            int st = steps[k];
            int* gk = g + 25 + k * 5;
            gk[0] = st;
            for (int j = 0; j < 4; ++j) gk[1 + j] = spos[t[st][j]];
        }
        ++ng;
    }
    meta[0] = ng;
}

__device__ __forceinline__ unsigned swz(unsigned a) {
    return a ^ (((((a >> 5) ^ (a >> 8) ^ (a >> 11)) & 7u)) << 2);
}

__global__ __launch_bounds__(NTHR, 4) void sweep_kernel(
    const float* __restrict__ src, float* __restrict__ dst,
    const int* __restrict__ meta, int sweep)
{
    if (sweep >= meta[0]) return;   // uniform early-exit for empty sweeps

    __shared__ float ldsR[TILE];
    __shared__ float ldsI[TILE];
    __shared__ float gsh[MAXG][512];     // interleaved (re,im) per gate
    __shared__ int s13[13], c11[11], gpos[MAXG][4], gstep[MAXG];
    __shared__ int ngat_sh;

    const int tid = threadIdx.x;
    const int* g = meta + 8 + sweep * GROUP_STRIDE;

    if (tid < 13) s13[tid] = g[1 + tid];
    else if (tid >= 16 && tid < 27) c11[tid - 16] = g[14 + (tid - 16)];
    else if (tid == 27) ngat_sh = g[0];
    else if (tid >= 32 && tid < 32 + MAXG * 5) {
        int k = (tid - 32) / 5, f = (tid - 32) % 5;
        if (f == 0) gstep[k] = g[25 + k * 5];
        else gpos[k][f - 1] = g[25 + k * 5 + f];
    }
    __syncthreads();

    const int ngat = ngat_sh;
    const float* gates = (const float*)0;  // set below via param trick? no — pass pointer
    // (gates pointer passed through meta? No: passed as kernel arg)
    (void)gates;

    // ---- addresses ----
    unsigned base = blockIdx.x;
    #pragma unroll
    for (int i = 0; i < TB; ++i) {
        const unsigned s = (unsigned)s13[i];
        base = ((base >> s) << (s + 1)) | (base & ((1u << s) - 1u));
    }
    unsigned ga[4], wa[4];
    #pragma unroll
    for (int p = 0; p < 4; ++p) {
        unsigned a = (unsigned)(p * 2048 + tid * 4);
        wa[p] = swz(a);
        unsigned spd = a;
        #pragma unroll
        for (int i = 0; i < 11; ++i) {
            const unsigned c = (unsigned)c11[i];
            spd = ((spd >> c) << (c + 1)) | (spd & ((1u << c) - 1u));
        }
        ga[p] = base | spd;
    }
    return; // placeholder (never emitted; real body below)
}

// NOTE: the above stub was restructured — full kernel follows.
__global__ __launch_bounds__(NTHR, 4) void sweep_full(
    const float* __restrict__ src, float* __restrict__ dst,
    const float* __restrict__ gates_g,
    const int* __restrict__ meta, int sweep)
{
    if (sweep >= meta[0]) return;

    __shared__ float ldsR[TILE];
    __shared__ float ldsI[TILE];
    __shared__ float gsh[MAXG][512];
    __shared__ int s13[13], c11[11], gpos[MAXG][4], gstep[MAXG];
    __shared__ int ngat_sh;

    const int tid = threadIdx.x;
    const int* g = meta + 8 + sweep * GROUP_STRIDE;

    if (tid < 13) s13[tid] = g[1 + tid];
    else if (tid >= 16 && tid < 27) c11[tid - 16] = g[14 + (tid - 16)];
    else if (tid == 27) ngat_sh = g[0];
    else if (tid >= 32 && tid < 32 + MAXG * 5) {
        int k = (tid - 32) / 5, f = (tid - 32) % 5;
        if (f == 0) gstep[k] = g[25 + k * 5];
        else gpos[k][f - 1] = g[25 + k * 5 + f];
    }
    __syncthreads();

    const int ngat = ngat_sh;

    // stage gates interleaved: gsh[k][2i]=re[i], [2i+1]=im[i]
    for (int k = 0; k < ngat; ++k) {
        const float* G = gates_g + (size_t)gstep[k] * 512;
        gsh[k][tid] = G[(tid & 1) * 256 + (tid >> 1)];
    }

    // ---- global addresses ----
    unsigned base = blockIdx.x;
    #pragma unroll
    for (int i = 0; i < TB; ++i) {
        const unsigned s = (unsigned)s13[i];
        base = ((base >> s) << (s + 1)) | (base & ((1u << s) - 1u));
    }
    unsigned ga[4], wa[4];
    #pragma unroll
    for (int p = 0; p < 4; ++p) {
        unsigned a = (unsigned)(p * 2048 + tid * 4);
        wa[p] = swz(a);
        unsigned spd = a;
        #pragma unroll
        for (int i = 0; i < 11; ++i) {
            const unsigned c = (unsigned)c11[i];
            spd = ((spd >> c) << (c + 1)) | (spd & ((1u << c) - 1u));
        }
        ga[p] = base | spd;
    }

    // ---- load: global -> swizzled LDS ----
    #pragma unroll
    for (int p = 0; p < 4; ++p) {
        *(float4*)(ldsR + wa[p]) = *(const float4*)(src + ga[p]);
        *(float4*)(ldsI + wa[p]) = *(const float4*)(src + NSTATE + ga[p]);
    }
    __syncthreads();

    // ---- apply gates in LDS ----
    for (int k = 0; k < ngat; ++k) {
        const int p0 = gpos[k][0], p1 = gpos[k][1], p2 = gpos[k][2], p3 = gpos[k][3];
        const unsigned tmask = (1u << p0) | (1u << p1) | (1u << p2) | (1u << p3);
        // group bits: tid's 9 bits over the 9 non-target tile positions
        unsigned gb = 0;
        {
            int bi = 0;
            for (int pos = 0; pos < TB; ++pos)
                if (!((tmask >> pos) & 1u)) { gb |= (((unsigned)tid >> bi) & 1u) << pos; ++bi; }
        }
        unsigned aa[16];
        float sr[16], si[16];
        #pragma unroll
        for (int h = 0; h < 16; ++h) {
            const unsigned a = gb
                | (((unsigned)h & 1u) << p0)
                | ((((unsigned)h >> 1) & 1u) << p1)
                | ((((unsigned)h >> 2) & 1u) << p2)
                | ((((unsigned)h >> 3) & 1u) << p3);
            const unsigned w = swz(a);
            aa[h] = w;
            sr[h] = ldsR[w];
            si[h] = ldsI[w];
        }
        const float* gk = gsh[k];
        #pragma unroll
        for (int go = 0; go < 16; ++go) {
            const float* row = gk + go * 32;
            float ar = 0.f, ai = 0.f;
            #pragma unroll
            for (int h2 = 0; h2 < 8; ++h2) {
                const float4 q = *(const float4*)(row + h2 * 4);
                const int h = h2 * 2;
                ar = fmaf(q.x, sr[h], ar);  ar = fmaf(-q.y, si[h], ar);
                ai = fmaf(q.x, si[h], ai);  ai = fmaf(q.y, sr[h], ai);
                ar = fmaf(q.z, sr[h + 1], ar);  ar = fmaf(-q.w, si[h + 1], ar);
                ai = fmaf(q.z, si[h + 1], ai);  ai = fmaf(q.w, sr[h + 1], ai);
            }
            ldsR[aa[go]] = ar;
            ldsI[aa[go]] = ai;
        }
        __syncthreads();
    }

    // ---- store: LDS -> global ----
    #pragma unroll
    for (int p = 0; p < 4; ++p) {
        *(float4*)(dst + ga[p])          = *(const float4*)(ldsR + wa[p]);
        *(float4*)(dst + NSTATE + ga[p]) = *(const float4*)(ldsI + wa[p]);
    }
}

extern "C" void kernel_launch(void* const* d_in, const int* in_sizes, int n_in,
                              void* d_out, int out_size, void* d_ws, size_t ws_size,
                              hipStream_t stream) {
    const float* state   = (const float*)d_in[0];
    const int*   targets = (const int*)d_in[1];
    const float* gates   = (const float*)d_in[2];
    float* out = (float*)d_out;
    int* meta = (int*)d_ws;

    plan_kernel<<<1, 64, 0, stream>>>(targets, meta);

    const dim3 block(NTHR);
    const dim3 grid(NSTATE / TILE);   // 2048 blocks

    sweep_full<<<grid, block, 0, stream>>>(state, out, gates, meta, 0);
    for (int s = 1; s < MAXG; ++s)
        sweep_full<<<grid, block, 0, stream>>>(out, out, gates, meta, s);
}

// Round 4
// 495.778 us; speedup vs baseline: 1.2193x; 1.0480x over previous
//
#include <hip/hip_runtime.h>

#define NQ 24
#define NSTATE (1u << NQ)      // 2^24 amps per plane
#define TB 13                  // tile bits
#define TILE (1u << TB)        // 8192 amps per tile
#define NTHR 512
#define SWEEP_STRIDE 288
#define META_HDR 16

// meta (ints, in d_ws):
// [0] n_sweeps
// sweep s at META_HDR + s*SWEEP_STRIDE:
//   [0]        n_gates (1..8)
//   [1..13]    s13: tile-bit -> global-bit positions, ascending ({0,1,2,3} forced first)
//   gate k at +16 + k*32:
//     [0]      step index
//     [1..16]  hs16: h -> OR-mask of h's 4 bits at target tile positions
//     [17..25] ntpos9: the 9 non-target tile positions, ascending

__global__ void plan_kernel(const int* __restrict__ targets_raw, int* __restrict__ meta)
{
    if (threadIdx.x != 0 || blockIdx.x != 0) return;
    // int64-vs-int32 detection (probes in-bounds both ways; row-0 targets are
    // distinct so at most one of the probed odd words is 0 in the int32 case)
    bool is64 = true;
    for (int i = 0; i < 4; ++i)
        if (targets_raw[2 * i + 1] != 0) { is64 = false; break; }

    int t[8][4]; unsigned tm[8];
    for (int s = 0; s < 8; ++s) {
        unsigned m = 0;
        for (int j = 0; j < 4; ++j) {
            int v = is64 ? targets_raw[2 * (s * 4 + j)] : targets_raw[s * 4 + j];
            t[s][j] = v; m |= 1u << v;
        }
        tm[s] = m;
    }

    int ng = 0, sp = 0;
    while (sp < 8) {
        unsigned mask = 0xFu;              // force bits 0..3 for coalescing
        int cnt = 0, steps[8];
        while (sp < 8 && cnt < 8) {        // consecutive-only fusion (order matters)
            unsigned nm = mask | tm[sp];
            if (__popc(nm) <= TB) { mask = nm; steps[cnt++] = sp++; }
            else break;
        }
        unsigned sm = mask;
        int need = TB - __popc(sm);
        for (int b = 0; b < NQ && need > 0; ++b)
            if (!((sm >> b) & 1u)) { sm |= 1u << b; --need; }

        int* base = meta + META_HDR + ng * SWEEP_STRIDE;
        base[0] = cnt;
        int spos[NQ]; int si = 0;
        for (int b = 0; b < NQ; ++b) {
            if ((sm >> b) & 1u) { spos[b] = si; base[1 + si] = b; ++si; }
            else spos[b] = -1;
        }
        for (int k = 0; k < cnt; ++k) {
            int st = steps[k];
            int* gk = base + 16 + k * 32;
            gk[0] = st;
            int pt[4];
            for (int j = 0; j < 4; ++j) pt[j] = spos[t[st][j]];
            for (int h = 0; h < 16; ++h)
                gk[1 + h] = ((h & 1) << pt[0]) | (((h >> 1) & 1) << pt[1])
                          | (((h >> 2) & 1) << pt[2]) | (((h >> 3) & 1) << pt[3]);
            const unsigned tmask =
                (1u << pt[0]) | (1u << pt[1]) | (1u << pt[2]) | (1u << pt[3]);
            int idx = 0;
            for (int pos = 0; pos < TB; ++pos)
                if (!((tmask >> pos) & 1u)) gk[17 + idx++] = pos;
        }
        ++ng;
    }
    meta[0] = ng;
}

// State tile in LDS as interleaved (re,im) float2. Gate coefficients consumed
// straight from global via uniform (scalar) loads -> SGPR operands in the FMAs.
__global__ __launch_bounds__(NTHR) void sweep_k(
    const float* __restrict__ src, float* __restrict__ dst,
    const float* __restrict__ gates, const int* __restrict__ meta, int sweep)
{
    if (sweep >= meta[0]) return;    // uniform early exit for empty sweeps

    __shared__ float lds[TILE * 2];  // 64 KB -> 2 blocks/CU
    const int tid = threadIdx.x;
    const int* sb = meta + META_HDR + sweep * SWEEP_STRIDE;
    const int ngat = sb[0];

    // block base: insert a zero at each tile-bit position (ascending)
    unsigned base = blockIdx.x;
    #pragma unroll
    for (int i = 0; i < TB; ++i) {
        const unsigned s = (unsigned)sb[1 + i];
        base = ((base >> s) << (s + 1)) | (base & ((1u << s) - 1u));
    }
    // thread part: tile addr a = c*2048 + tid*4; bits 0..3 -> global 0..3,
    // bits 4..10 (tid bits 2..8) -> s13[4..10], bits 11..12 (c) -> s13[11..12]
    unsigned ga0 = base | ((unsigned)(tid * 4) & 15u);
    #pragma unroll
    for (int i = 0; i < 7; ++i)
        ga0 |= (((unsigned)tid >> (2 + i)) & 1u) << sb[5 + i];

    unsigned ga_[4], w_[4];
    #pragma unroll
    for (int c = 0; c < 4; ++c) {
        ga_[c] = ga0 | (((unsigned)c & 1u) << sb[12])
                     | ((((unsigned)c >> 1) & 1u) << sb[13]);
        const unsigned a = (unsigned)(c * 2048 + tid * 4);
        w_[c] = a ^ (((a >> 7) & 0x1Fu) << 2);   // float2-index swizzle, keeps bits 0,1
    }

    // ---- load: coalesced 64B-line float4 -> interleaved swizzled LDS ----
    #pragma unroll
    for (int c = 0; c < 4; ++c) {
        const float4 r4 = *(const float4*)(src + ga_[c]);
        const float4 i4 = *(const float4*)(src + NSTATE + ga_[c]);
        float* p = lds + 2 * w_[c];
        ((float4*)p)[0] = make_float4(r4.x, i4.x, r4.y, i4.y);
        ((float4*)p)[1] = make_float4(r4.z, i4.z, r4.w, i4.w);
    }
    __syncthreads();

    // ---- fused gates ----
    for (int k = 0; k < ngat; ++k) {
        const int* gk = sb + 16 + k * 32;
        const int step = __builtin_amdgcn_readfirstlane(gk[0]);
        const float* __restrict__ Gre = gates + (size_t)step * 512;
        const float* __restrict__ Gim = Gre + 256;

        // group base: tid's 9 bits at the 9 non-target tile positions
        unsigned gb = 0;
        #pragma unroll
        for (int i = 0; i < 9; ++i)
            gb |= (((unsigned)tid >> i) & 1u) << gk[17 + i];

        float sr[16], si[16]; unsigned aw[16];
        #pragma unroll
        for (int h = 0; h < 16; ++h) {
            const unsigned idx = gb | (unsigned)gk[1 + h];
            const unsigned w = idx ^ (((idx >> 7) & 0x1Fu) << 2);
            aw[h] = w;
            const float2 v = *(const float2*)(lds + 2 * w);
            sr[h] = v.x; si[h] = v.y;
        }
        #pragma unroll
        for (int g = 0; g < 16; ++g) {
            float ar = 0.f, ai = 0.f;
            #pragma unroll
            for (int h = 0; h < 16; ++h) {
                const float grv = Gre[g * 16 + h];   // uniform -> s_load -> SGPR
                const float giv = Gim[g * 16 + h];
                ar = fmaf(grv, sr[h], ar);
                ar = fmaf(-giv, si[h], ar);
                ai = fmaf(grv, si[h], ai);
                ai = fmaf(giv, sr[h], ai);
            }
            // own slots only (groups partition the tile) -> safe immediate write
            *(float2*)(lds + 2 * aw[g]) = make_float2(ar, ai);
        }
        __syncthreads();
    }

    // ---- store: swizzled LDS -> coalesced float4 ----
    #pragma unroll
    for (int c = 0; c < 4; ++c) {
        const float* p = lds + 2 * w_[c];
        const float4 q0 = ((const float4*)p)[0];
        const float4 q1 = ((const float4*)p)[1];
        *(float4*)(dst + ga_[c])          = make_float4(q0.x, q0.z, q1.x, q1.z);
        *(float4*)(dst + NSTATE + ga_[c]) = make_float4(q0.y, q0.w, q1.y, q1.w);
    }
}

extern "C" void kernel_launch(void* const* d_in, const int* in_sizes, int n_in,
                              void* d_out, int out_size, void* d_ws, size_t ws_size,
                              hipStream_t stream) {
    const float* state   = (const float*)d_in[0];
    const int*   targets = (const int*)d_in[1];
    const float* gates   = (const float*)d_in[2];
    float* out = (float*)d_out;
    int* meta = (int*)d_ws;

    plan_kernel<<<1, 64, 0, stream>>>(targets, meta);

    const dim3 block(NTHR);
    const dim3 grid(NSTATE / TILE);   // 2048 blocks

    sweep_k<<<grid, block, 0, stream>>>(state, out, gates, meta, 0);
    for (int s = 1; s < 4; ++s)
        sweep_k<<<grid, block, 0, stream>>>(out, out, gates, meta, s);
}